// Round 7
// baseline (239.102 us; speedup 1.0000x reference)
//
#include <hip/hip_runtime.h>
#include <stdint.h>

#define DEV __device__ __forceinline__

typedef __attribute__((ext_vector_type(8))) short bf16x8;
typedef __attribute__((ext_vector_type(4))) float f32x4;
typedef __attribute__((ext_vector_type(16))) float f32x16;
typedef __attribute__((ext_vector_type(8))) unsigned short ushort8;

DEV unsigned short f2bf(float f) {
  unsigned u = __float_as_uint(f);
  return (unsigned short)((u + 0x7fffu + ((u >> 16) & 1u)) >> 16);
}
DEV float bf2f(unsigned short h) { return __uint_as_float(((unsigned)h) << 16); }

DEV unsigned cvtpk(float lo, float hi) {
  unsigned r;
  asm("v_cvt_pk_bf16_f32 %0, %1, %2" : "=v"(r) : "v"(lo), "v"(hi));
  return r;
}
DEV void pl32swap(unsigned& a, unsigned& b) {
  asm volatile("v_permlane32_swap_b32 %0, %1" : "+v"(a), "+v"(b));
}

DEV void async16(const void* g, void* l) {
  __builtin_amdgcn_global_load_lds((const __attribute__((address_space(1))) void*)g,
                                   (__attribute__((address_space(3))) void*)l, 16, 0, 0);
}

// ================= mega prep: mask | Wbf | Wo(+T) | W1b | W1ab | tgtfeats | LN | c1 | bo =====
__global__ void k_prep_all(const unsigned char* __restrict__ mask, const float4* __restrict__ ipw,
                           const float* __restrict__ opw, const float* __restrict__ g1w,
                           const float* __restrict__ tgt, const float* __restrict__ feats,
                           const float* __restrict__ sup,
                           const float* __restrict__ qw, const float* __restrict__ qb,
                           const float* __restrict__ kw, const float* __restrict__ kb,
                           const float* __restrict__ bo,
                           unsigned short* __restrict__ maskbf, ushort4* __restrict__ Wbf,
                           unsigned short* __restrict__ Wobf, unsigned short* __restrict__ WoT,
                           unsigned short* __restrict__ Wg1attn, unsigned short* __restrict__ Wg1ab,
                           unsigned short* __restrict__ tgtfeats, unsigned short* __restrict__ qin,
                           unsigned short* __restrict__ kvin, float* __restrict__ pbias) {
  __shared__ unsigned short tl[64][65];
  __shared__ float red[8];
  __shared__ int sr[4];
  int bid = blockIdx.x, t = threadIdx.x;
  if (bid < 16) {
    // mask dtype detect + bf16 additive mask (valid -> -8 shift, invalid -> -1e30)
    int any = 0;
    for (int i = t; i < 4096; i += 256)
      if ((i & 3) != 0 && mask[i] != 0) any = 1;
    unsigned long long ball = __ballot(any);
    if ((t & 63) == 0) sr[t >> 6] = (ball != 0ULL) ? 1 : 0;
    __syncthreads();
    int isbool = sr[0] | sr[1] | sr[2] | sr[3];
    int i = bid * 256 + t;
    int v = isbool ? (mask[i] != 0) : (((const int*)mask)[i] != 0);
    maskbf[i] = v ? f2bf(-8.0f) : f2bf(-1e30f);
  } else if (bid < 3088) {
    int i = (bid - 16) * 256 + t;
    float4 v = ipw[i];
    ushort4 o; o.x = f2bf(v.x); o.y = f2bf(v.y); o.z = f2bf(v.z); o.w = f2bf(v.w);
    Wbf[i] = o;
  } else if (bid < 3344) {
    // out_proj: bf16 convert (straight) + transpose into WoT via LDS tile
    int b2 = bid - 3088;
    int r0 = (b2 >> 4) * 64, c0 = (b2 & 15) * 64;
#pragma unroll
    for (int i = 0; i < 16; i++) {
      int idx = i * 256 + t, rr = idx >> 6, cc = idx & 63;
      unsigned short bv = f2bf(opw[(size_t)(r0 + rr) * 1024 + c0 + cc]);
      Wobf[(size_t)(r0 + rr) * 1024 + c0 + cc] = bv;
      tl[cc][rr] = bv;
    }
    __syncthreads();
#pragma unroll
    for (int i = 0; i < 16; i++) {
      int idx = i * 256 + t, rr = idx & 63, cc = idx >> 6;
      WoT[(size_t)(c0 + cc) * 1024 + r0 + rr] = tl[cc][rr];
    }
  } else if (bid < 4368) {
    // Wg1attn[n][d] = gate_w1[n][1024+d]
    int r = bid - 3344;
    const float* src = g1w + (size_t)r * 2051 + 1024;
    int c = t * 4;
    ushort4 o;
    o.x = f2bf(src[c]); o.y = f2bf(src[c + 1]); o.z = f2bf(src[c + 2]); o.w = f2bf(src[c + 3]);
    *(ushort4*)(Wg1attn + (size_t)r * 1024 + c) = o;
  } else if (bid < 5392) {
    // Wg1ab[n][0:1024]=cols 0:1024; [1024:1027]=cols 2048:2051; pad to 1056
    int r = bid - 4368;
    const float* src = g1w + (size_t)r * 2051;
    for (int q = t; q < 264; q += 256) {
      int c = q * 4;
      ushort4 o;
#pragma unroll
      for (int j = 0; j < 4; j++) {
        int cs = c + j;
        float v = (cs < 1024) ? src[cs] : ((cs < 1027) ? src[1024 + cs] : 0.f);
        ((unsigned short*)&o)[j] = f2bf(v);
      }
      *(ushort4*)(Wg1ab + (size_t)r * 1056 + c) = o;
    }
  } else if (bid < 7440) {
    // tgtfeats[t][0:1024]=target; [1024:1027]=feats; pad to 1056
    int r = bid - 5392;
    for (int q = t; q < 264; q += 256) {
      int c = q * 4;
      ushort4 o;
#pragma unroll
      for (int j = 0; j < 4; j++) {
        int cs = c + j;
        float v = (cs < 1024) ? tgt[(size_t)r * 1024 + cs]
                              : ((cs < 1027) ? feats[r * 3 + cs - 1024] : 0.f);
        ((unsigned short*)&o)[j] = f2bf(v);
      }
      *(ushort4*)(tgtfeats + (size_t)r * 1056 + c) = o;
    }
  } else if (bid < 13584) {
    // layernorm rows (0..2047 target->qin, 2048..6143 support->kvin)
    int row = bid - 7440;
    const float *x, *w, *bb2;
    unsigned short* y;
    if (row < 2048) { x = tgt + (size_t)row * 1024; w = qw; bb2 = qb; y = qin + (size_t)row * 1024; }
    else { int r = row - 2048; x = sup + (size_t)r * 1024; w = kw; bb2 = kb; y = kvin + (size_t)r * 1024; }
    float4 v = ((const float4*)x)[t];
    float s = v.x + v.y + v.z + v.w;
    float ss = v.x * v.x + v.y * v.y + v.z * v.z + v.w * v.w;
#pragma unroll
    for (int m = 32; m >= 1; m >>= 1) { s += __shfl_xor(s, m); ss += __shfl_xor(ss, m); }
    int wv = t >> 6;
    if ((t & 63) == 0) { red[wv] = s; red[4 + wv] = ss; }
    __syncthreads();
    s = red[0] + red[1] + red[2] + red[3];
    ss = red[4] + red[5] + red[6] + red[7];
    float mean = s * (1.f / 1024.f);
    float var = ss * (1.f / 1024.f) - mean * mean;
    float inv = rsqrtf(var + 1e-5f);
    float4 wv4 = ((const float4*)w)[t];
    float4 bv4 = ((const float4*)bb2)[t];
    ushort4 o;
    o.x = f2bf((v.x - mean) * inv * wv4.x + bv4.x);
    o.y = f2bf((v.y - mean) * inv * wv4.y + bv4.y);
    o.z = f2bf((v.z - mean) * inv * wv4.z + bv4.z);
    o.w = f2bf((v.w - mean) * inv * wv4.w + bv4.w);
    ((ushort4*)y)[t] = o;
  } else if (bid < 13648) {
    // c1[n] = sum_d bo[d] * gate_w1[n][1024+d]  -> pbias[1024+n]
    int b7 = bid - 13584;
    int n = b7 * 16 + (t >> 4), l16 = t & 15;
    const float* wrow = g1w + (size_t)n * 2051 + 1024;
    float s = 0.f;
    for (int j = 0; j < 64; j++) s += bo[l16 + 16 * j] * wrow[l16 + 16 * j];
#pragma unroll
    for (int m = 1; m < 16; m <<= 1) s += __shfl_xor(s, m);
    if (l16 == 0) pbias[1024 + n] = s;
  } else {
    ((float4*)pbias)[t] = ((const float4*)bo)[t];  // pbias[0:1024] = out_proj_b
  }
}

// ================= bf16 GEMM body: C[M,N] = (A[M,K] * B[N,K]^T [+bias]) * oscale ==========
// OUTMODE: 0 = bf16 out, 1 = f32 out, 4 = bf16 out without bias
template <int BM, int BN, int OUTMODE>
DEV void gemm_body(const unsigned short* __restrict__ A, const unsigned short* __restrict__ B,
                   const float* __restrict__ bias, void* __restrict__ Cout, int N, int K,
                   int m0, int n0, float oscale, unsigned short* As, unsigned short* Bs) {
  constexpr int WM = BM / 2, WN = BN / 2, FM = WM / 16, FN = WN / 16;
  int tid = threadIdx.x, l = tid & 63, w = tid >> 6;
  int wm = w >> 1, wn = w & 1;

  f32x4 acc[FM][FN];
#pragma unroll
  for (int m = 0; m < FM; m++)
#pragma unroll
    for (int n = 0; n < FN; n++) acc[m][n] = (f32x4){0.f, 0.f, 0.f, 0.f};

  auto stage = [&](int buf, int k0) {
#pragma unroll
    for (int i = 0; i < BM / 64; i++) {
      int r = i * 64 + w * 16 + (l >> 2);
      int cb = ((l & 3) * 16) ^ (((r >> 1) & 3) << 4);
      async16((const char*)A + (((size_t)(m0 + r) * K + k0) * 2 + cb),
              (char*)As + buf * (BM * 64) + (i * 64 + w * 16) * 64);
    }
#pragma unroll
    for (int i = 0; i < BN / 64; i++) {
      int r = i * 64 + w * 16 + (l >> 2);
      int cb = ((l & 3) * 16) ^ (((r >> 1) & 3) << 4);
      async16((const char*)B + (((size_t)(n0 + r) * K + k0) * 2 + cb),
              (char*)Bs + buf * (BN * 64) + (i * 64 + w * 16) * 64);
    }
  };

  int nk = K / 32;
  stage(0, 0);
  __syncthreads();
  int cur = 0;
  for (int kt = 0; kt < nk; kt++) {
    if (kt + 1 < nk) stage(cur ^ 1, (kt + 1) * 32);
    bf16x8 af[FM], bfr[FN];
#pragma unroll
    for (int m = 0; m < FM; m++) {
      int rr = wm * WM + m * 16 + (l & 15);
      af[m] = *(const bf16x8*)((const char*)As + cur * (BM * 64) + rr * 64 +
                               ((16 * (l >> 4)) ^ (((rr >> 1) & 3) << 4)));
    }
#pragma unroll
    for (int n = 0; n < FN; n++) {
      int rr = wn * WN + n * 16 + (l & 15);
      bfr[n] = *(const bf16x8*)((const char*)Bs + cur * (BN * 64) + rr * 64 +
                                ((16 * (l >> 4)) ^ (((rr >> 1) & 3) << 4)));
    }
    __builtin_amdgcn_s_setprio(1);
#pragma unroll
    for (int m = 0; m < FM; m++)
#pragma unroll
      for (int n = 0; n < FN; n++)
        acc[m][n] = __builtin_amdgcn_mfma_f32_16x16x32_bf16(af[m], bfr[n], acc[m][n], 0, 0, 0);
    __builtin_amdgcn_s_setprio(0);
    __syncthreads();
    cur ^= 1;
  }

#pragma unroll
  for (int m = 0; m < FM; m++)
#pragma unroll
    for (int n = 0; n < FN; n++)
#pragma unroll
      for (int r = 0; r < 4; r++) {
        int gr = m0 + wm * WM + m * 16 + (l >> 4) * 4 + r;
        int gc = n0 + wn * WN + n * 16 + (l & 15);
        float v = acc[m][n][r];
        if (OUTMODE != 4) v += bias[gc];
        v *= oscale;
        if (OUTMODE == 1)
          ((float*)Cout)[(size_t)gr * N + gc] = v;
        else
          ((unsigned short*)Cout)[(size_t)gr * N + gc] = f2bf(v);
      }
}

// ======== pre-attention mega-GEMM: Q(x0.125) | KV | h1=tgtfeats@W1ab^T | F=W1b@Wo ========
// launch_bounds(256,4): 4 blocks/CU (LDS 32KB x4 = 128KB, VGPR cap 128 > 64 used).
__global__ __launch_bounds__(256, 4)
void k_mm1(const unsigned short* __restrict__ qin, const unsigned short* __restrict__ kvin,
           const unsigned short* __restrict__ tgtfeats, const unsigned short* __restrict__ Wg1attn,
           const unsigned short* __restrict__ Wbf, const unsigned short* __restrict__ Wg1ab,
           const unsigned short* __restrict__ WoT, const float* __restrict__ ipb,
           const float* __restrict__ g1b, unsigned short* __restrict__ qbuf,
           unsigned short* __restrict__ kvbuf, float* __restrict__ h1buf,
           unsigned short* __restrict__ Fbf) {
  __shared__ __align__(16) unsigned short As[2 * 128 * 32];
  __shared__ __align__(16) unsigned short Bs[2 * 128 * 32];
  int cpx = gridDim.x >> 3;
  int orig = (blockIdx.x & 7) * cpx + (blockIdx.x >> 3);
  if (orig < 128) {
    gemm_body<128, 128, 0>(qin, Wbf, ipb, qbuf, 1024, 1024, (orig >> 3) * 128, (orig & 7) * 128,
                           0.125f, As, Bs);
  } else if (orig < 640) {
    int t = orig - 128;
    gemm_body<128, 128, 0>(kvin, Wbf + 1024 * 1024, ipb + 1024, kvbuf, 2048, 1024,
                           (t >> 4) * 128, (t & 15) * 128, 1.0f, As, Bs);
  } else if (orig < 768) {
    int t = orig - 640;
    gemm_body<128, 128, 1>(tgtfeats, Wg1ab, g1b, h1buf, 1024, 1056, (t >> 3) * 128,
                           (t & 7) * 128, 1.0f, As, Bs);
  } else {
    int t = orig - 768;
    gemm_body<64, 64, 4>(Wg1attn, WoT, nullptr, Fbf, 1024, 1024, (t >> 4) * 64, (t & 15) * 64,
                         1.0f, As, Bs);
  }
}

// ========= post-attention GEMM: hc[2048][2048] = ctx @ [Wo ; F]^T + [bo ; c1] (f32) =========
__global__ __launch_bounds__(256, 4)
void k_mm2(const unsigned short* __restrict__ ctx, const unsigned short* __restrict__ Bw,
           const float* __restrict__ pbias, float* __restrict__ hc) {
  __shared__ __align__(16) unsigned short As[2 * 128 * 32];
  __shared__ __align__(16) unsigned short Bs[2 * 64 * 32];
  int cpx = gridDim.x >> 3;
  int orig = (blockIdx.x & 7) * cpx + (blockIdx.x >> 3);
  gemm_body<128, 64, 1>(ctx, Bw, pbias, hc, 2048, 1024, (orig >> 5) * 128, (orig & 31) * 64,
                        1.0f, As, Bs);
}

// ================= V transpose: kvb[:, 1024+d] -> vt[b*1024+d][kv] =================
__global__ void k_transpose_v(const unsigned short* __restrict__ kvb,
                              unsigned short* __restrict__ vt) {
  __shared__ unsigned short t[64][66];
  int kv0 = blockIdx.x * 64, d0 = blockIdx.y * 64, b = blockIdx.z;
  for (int i = threadIdx.x; i < 4096; i += 256) {
    int r = i >> 6, c = i & 63;
    t[r][c] = kvb[(size_t)(b * 2048 + kv0 + r) * 2048 + 1024 + d0 + c];
  }
  __syncthreads();
  for (int i = threadIdx.x; i < 4096; i += 256) {
    int r = i >> 6, c = i & 63;
    vt[(size_t)(b * 1024 + d0 + r) * 2048 + kv0 + c] = t[c][r];
  }
}

// ========== flash attention: 32x32 swapped-QK, in-register softmax ==========
// launch_bounds(256,3): 3 blocks/CU (LDS 17KB, VGPR cap ~168).
__global__ __launch_bounds__(256, 3)
void k_attn(const unsigned short* __restrict__ qb, const unsigned short* __restrict__ kvb,
            const unsigned short* __restrict__ vt, const unsigned short* __restrict__ maskbf,
            unsigned short* __restrict__ pot, float* __restrict__ plsum) {
  __shared__ __align__(16) unsigned short Kt[2][32 * 64];
  __shared__ __align__(16) unsigned short Vt[2][64 * 32];
  __shared__ __align__(16) unsigned short mls[512];
  int tid = threadIdx.x, l = tid & 63, w = tid >> 6;
  int hi = l >> 5, q32 = l & 31;
  int id = blockIdx.x;
  int hb = id & 31, rest = id >> 5;
  int qt = rest >> 2, seg = rest & 3;
  int h = hb & 15, b = hb >> 4;
  int qrow = qt * 128 + w * 32 + q32;
  int kv0base = seg * 512;

  bf16x8 fq[4];
  const char* qsrc = (const char*)qb + (((size_t)(b * 1024 + qrow)) * 1024 + h * 64 + hi * 8) * 2;
#pragma unroll
  for (int i = 0; i < 4; i++) fq[i] = *(const bf16x8*)(qsrc + i * 32);

  bf16x8 onesB = {0, 0, 0, 0, 0, 0, 0, 0};
  if (hi == 0) onesB[0] = (short)0x3F80;

  f32x16 oa0 = {0, 0, 0, 0, 0, 0, 0, 0, 0, 0, 0, 0, 0, 0, 0, 0};
  f32x16 oa1 = {0, 0, 0, 0, 0, 0, 0, 0, 0, 0, 0, 0, 0, 0, 0, 0};
  float plocal = 0.f;

  if (w == 0)
    async16((const char*)maskbf + ((size_t)b * 2048 + kv0base) * 2 + l * 16, (char*)mls);

  const char* kgb = (const char*)kvb + ((size_t)(b * 2048)) * 4096 + h * 128;
  const char* vgb = (const char*)vt + ((size_t)(b * 1024 + h * 64)) * 4096;
  int kcb = (((l & 7) ^ ((l >> 3) & 7)) << 4);
  int vcb = (((l & 3) ^ ((l >> 3) & 3)) << 4);

  auto stage = [&](int buf, int kv0) {
    async16(kgb + (size_t)(kv0 + w * 8 + (l >> 3)) * 4096 + kcb, (char*)&Kt[buf][0] + w * 1024);
    async16(vgb + (size_t)(w * 16 + (l >> 2)) * 4096 + (size_t)kv0 * 2 + vcb,
            (char*)&Vt[buf][0] + w * 1024);
  };

  stage(0, kv0base);
  __syncthreads();
  int cur = 0;

  int kfs = q32 & 7;
  int vfs = (q32 >> 1) & 3;

  for (int t = 0; t < 16; t++) {
    int kv0 = kv0base + t * 32;
    if (t < 15) stage(cur ^ 1, kv0 + 32);

    f32x16 sac = {0, 0, 0, 0, 0, 0, 0, 0, 0, 0, 0, 0, 0, 0, 0, 0};
    const char* kt = (const char*)&Kt[cur][0];
    __builtin_amdgcn_s_setprio(1);
#pragma unroll
    for (int i = 0; i < 4; i++) {
      bf16x8 ka = *(const bf16x8*)(kt + q32 * 128 + (((i * 2 + hi) ^ kfs) << 4));
      sac = __builtin_amdgcn_mfma_f32_32x32x16_bf16(ka, fq[i], sac, 0, 0, 0);
    }
    unsigned short mv = mls[t * 32 + q32];
    bf16x8 ma = {0, 0, 0, 0, 0, 0, 0, 0};
    if (hi == 0) ma[0] = (short)mv;
    sac = __builtin_amdgcn_mfma_f32_32x32x16_bf16(ma, onesB, sac, 0, 0, 0);
    __builtin_amdgcn_s_setprio(0);

    float p[16];
#pragma unroll
    for (int j = 0; j < 16; j++) p[j] = __expf(sac[j]);
#pragma unroll
    for (int j = 0; j < 16; j++) plocal += p[j];

    bf16x8 pf[2];
#pragma unroll
    for (int c = 0; c < 2; c++) {
      unsigned A0 = cvtpk(p[c * 8 + 0], p[c * 8 + 1]);
      unsigned A1 = cvtpk(p[c * 8 + 2], p[c * 8 + 3]);
      unsigned B0 = cvtpk(p[c * 8 + 4], p[c * 8 + 5]);
      unsigned B1 = cvtpk(p[c * 8 + 6], p[c * 8 + 7]);
      pl32swap(A0, B0);
      pl32swap(A1, B1);
      unsigned fr[4] = {A0, A1, B0, B1};
      pf[c] = *(const bf16x8*)fr;
    }

    const char* vtb = (const char*)&Vt[cur][0];
    __builtin_amdgcn_s_setprio(1);
#pragma unroll
    for (int c = 0; c < 2; c++) {
      bf16x8 va0 = *(const bf16x8*)(vtb + q32 * 64 + (((c * 2 + hi) ^ vfs) << 4));
      bf16x8 va1 = *(const bf16x8*)(vtb + (32 + q32) * 64 + (((c * 2 + hi) ^ vfs) << 4));
      oa0 = __builtin_amdgcn_mfma_f32_32x32x16_bf16(va0, pf[c], oa0, 0, 0, 0);
      oa1 = __builtin_amdgcn_mfma_f32_32x32x16_bf16(va1, pf[c], oa1, 0, 0, 0);
    }
    __builtin_amdgcn_s_setprio(0);
    __syncthreads();
    cur ^= 1;
  }

  float ptot = plocal + __shfl_xor(plocal, 32);
  if (hi == 0) plsum[((size_t)seg * 2048 + b * 1024 + qrow) * 16 + h] = ptot;

  size_t pb = (((size_t)seg * 2 + b) * 16 + h) * 64;
#pragma unroll
  for (int j = 0; j < 16; j++) {
    int d0 = (j & 3) + 8 * (j >> 2) + 4 * hi;
    pot[(pb + d0) * 1024 + qrow] = f2bf(oa0[j]);
    pot[(pb + 32 + d0) * 1024 + qrow] = f2bf(oa1[j]);
  }
}

// ========== combine kv-split: ctx[q][d] = sum_seg O^T / sum_seg lsum (+transpose) ==========
__global__ void k_combine_t(const unsigned short* __restrict__ pot,
                            const float* __restrict__ plsum, unsigned short* __restrict__ ctx) {
  __shared__ float sinv[64];
  __shared__ __align__(16) unsigned short tl[64][72];
  int t = threadIdx.x;
  int id = blockIdx.x;
  int qt2 = id & 15, bh = id >> 4, h = bh & 15, b = bh >> 4;
  int q0 = qt2 * 64;

  if (t < 64) {
    float s = 0.f;
#pragma unroll
    for (int seg = 0; seg < 4; seg++)
      s += plsum[((size_t)seg * 2048 + b * 1024 + q0 + t) * 16 + h];
    sinv[t] = 1.f / s;
  }

  int d = t >> 2, qo = (t & 3) * 16;
  float acc[16];
#pragma unroll
  for (int j = 0; j < 16; j++) acc[j] = 0.f;
#pragma unroll
  for (int seg = 0; seg < 4; seg++) {
    size_t base = ((((size_t)seg * 2 + b) * 16 + h) * 64 + d) * 1024 + q0 + qo;
    ushort8 v0 = *(const ushort8*)(pot + base);
    ushort8 v1 = *(const ushort8*)(pot + base + 8);
#pragma unroll
    for (int j = 0; j < 8; j++) { acc[j] += bf2f(v0[j]); acc[8 + j] += bf2f(v1[j]); }
  }
  __syncthreads();
#pragma unroll
  for (int j = 0; j < 16; j++) tl[qo + j][d] = f2bf(acc[j] * sinv[qo + j]);
  __syncthreads();

  int q = t >> 2, dof = (t & 3) * 16;
  ushort8 a = *(const ushort8*)&tl[q][dof];
  ushort8 c8 = *(const ushort8*)&tl[q][dof + 8];
  size_t ob = ((size_t)(b * 1024 + q0 + q)) * 1024 + h * 64 + dof;
  *(ushort8*)(ctx + ob) = a;
  *(ushort8*)(ctx + ob + 8) = c8;
}

// ===== final: gelu(h1+hattn)·w2 -> sigmoid gate; fused residual; LN; outputs =====
__global__ void k_gatefinal(const float* __restrict__ h1, const float* __restrict__ hc,
                            const float* __restrict__ w2, const float* __restrict__ b2,
                            const float* __restrict__ target, const float* __restrict__ w,
                            const float* __restrict__ bb, float* __restrict__ out,
                            float* __restrict__ gout) {
  int row = blockIdx.x, t = threadIdx.x;
  float4 h1v = ((const float4*)(h1 + (size_t)row * 1024))[t];
  float4 hav = ((const float4*)(hc + (size_t)row * 2048 + 1024))[t];
  float4 w2v = ((const float4*)w2)[t];
  float4 g4;
  g4.x = h1v.x + hav.x; g4.y = h1v.y + hav.y; g4.z = h1v.z + hav.z; g4.w = h1v.w + hav.w;
  g4.x = 0.5f * g4.x * (1.f + erff(g4.x * 0.70710678118f));
  g4.y = 0.5f * g4.y * (1.f + erff(g4.y * 0.70710678118f));
  g4.z = 0.5f * g4.z * (1.f + erff(g4.z * 0.70710678118f));
  g4.w = 0.5f * g4.w * (1.f + erff(g4.w * 0.70710678118f));
  float s = g4.x * w2v.x + g4.y * w2v.y + g4.z * w2v.z + g4.w * w2v.w;
#pragma unroll
  for (int m = 32; m >= 1; m >>= 1) s += __shfl_xor(s, m);
  __shared__ float red[8];
  __shared__ float gsh;
  if ((t & 63) == 0) red[t >> 6] = s;
  __syncthreads();
  if (t == 0) {
    float tt = red[0] + red[1] + red[2] + red[3] + b2[0];
    float gv = 1.f / (1.f + __expf(-tt));
    gsh = gv;
    gout[row] = gv;
  }
  __syncthreads();
  float gv = gsh;

  float4 tg = ((const float4*)(target + (size_t)row * 1024))[t];
  float4 a = ((const float4*)(hc + (size_t)row * 2048))[t];  // attn_out cols 0:1024
  float4 y;
  y.x = (2.f - gv) * tg.x + gv * a.x;
  y.y = (2.f - gv) * tg.y + gv * a.y;
  y.z = (2.f - gv) * tg.z + gv * a.z;
  y.w = (2.f - gv) * tg.w + gv * a.w;
  float sm = y.x + y.y + y.z + y.w;
  float ss = y.x * y.x + y.y * y.y + y.z * y.z + y.w * y.w;
#pragma unroll
  for (int m = 32; m >= 1; m >>= 1) { sm += __shfl_xor(sm, m); ss += __shfl_xor(ss, m); }
  if ((t & 63) == 0) { red[t >> 6] = sm; red[4 + (t >> 6)] = ss; }
  __syncthreads();
  sm = red[0] + red[1] + red[2] + red[3];
  ss = red[4] + red[5] + red[6] + red[7];
  float mean = sm * (1.f / 1024.f);
  float var = ss * (1.f / 1024.f) - mean * mean;
  float inv = rsqrtf(var + 1e-5f);
  float4 wv4 = ((const float4*)w)[t];
  float4 bv4 = ((const float4*)bb)[t];
  float4 o;
  o.x = (y.x - mean) * inv * wv4.x + bv4.x;
  o.y = (y.y - mean) * inv * wv4.y + bv4.y;
  o.z = (y.z - mean) * inv * wv4.z + bv4.z;
  o.w = (y.w - mean) * inv * wv4.w + bv4.w;
  ((float4*)(out + (size_t)row * 1024))[t] = o;
}

extern "C" void kernel_launch(void* const* d_in, const int* in_sizes, int n_in,
                              void* d_out, int out_size, void* d_ws, size_t ws_size,
                              hipStream_t stream) {
  const float* target     = (const float*)d_in[0];
  const float* support    = (const float*)d_in[1];
  const float* feats      = (const float*)d_in[2];
  const void*  maskp      = d_in[3];
  const float* ln_q_w     = (const float*)d_in[4];
  const float* ln_q_b     = (const float*)d_in[5];
  const float* ln_kv_w    = (const float*)d_in[6];
  const float* ln_kv_b    = (const float*)d_in[7];
  const float* out_ln_w   = (const float*)d_in[8];
  const float* out_ln_b   = (const float*)d_in[9];
  const float* in_proj_w  = (const float*)d_in[10];
  const float* in_proj_b  = (const float*)d_in[11];
  const float* out_proj_w = (const float*)d_in[12];
  const float* out_proj_b = (const float*)d_in[13];
  const float* gate_w1    = (const float*)d_in[14];
  const float* gate_b1    = (const float*)d_in[15];
  const float* gate_w2    = (const float*)d_in[16];
  const float* gate_b2    = (const float*)d_in[17];

  if (ws_size < 109789184ULL) return;  // ~110 MB scratch

  char* ws = (char*)d_ws;
  unsigned short* Wbf      = (unsigned short*)(ws + 0);          // in_proj bf16 [3072][1024]
  unsigned short* Wobf     = (unsigned short*)(ws + 6291456);    // out_proj bf16 [1024][1024]
  unsigned short* Fbf      = (unsigned short*)(ws + 8388608);    // F bf16 [1024][1024] (contig w/ Wobf)
  unsigned short* WoT      = (unsigned short*)(ws + 10485760);   // Wo^T bf16 [1024][1024]
  unsigned short* Wg1attn  = (unsigned short*)(ws + 12582912);   // gate_w1[:,1024:2048] bf16
  unsigned short* Wg1ab    = (unsigned short*)(ws + 14680064);   // gate_w1[:,{0:1024,2048:2051}] pad 1056
  unsigned short* tgtfeats = (unsigned short*)(ws + 16842752);   // [target|feats|pad] bf16 [2048][1056]
  unsigned short* qin      = (unsigned short*)(ws + 21168128);   // LN(target) bf16
  unsigned short* kvin     = (unsigned short*)(ws + 25362432);   // LN(support) bf16
  unsigned short* qbuf     = (unsigned short*)(ws + 33751040);   // Q bf16 (x0.125)
  unsigned short* kvbuf    = (unsigned short*)(ws + 37945344);   // K|V bf16 [4096][2048]
  unsigned short* vtbuf    = (unsigned short*)(ws + 54722560);   // V^T bf16 [2][1024][2048]
  float*          h1buf    = (float*)(ws + 63111168);            // h1 f32 [2048][1024]
  unsigned short* pot      = (unsigned short*)(ws + 71499776);   // O^T partials bf16
  float*          plsum    = (float*)(ws + 88276992);            // lsum f32 [4][2048][16]
  unsigned short* ctx      = (unsigned short*)(ws + 88801280);   // ctx bf16 [2048][1024]
  float*          hc       = (float*)(ws + 92995584);            // [attn_out | h_attn] f32 [2048][2048]
  float*          pbias    = (float*)(ws + 109772800);           // [bo ; c1] f32 [2048]
  unsigned short* maskbf   = (unsigned short*)(ws + 109780992);  // additive mask bf16 [4096]

  float* outp = (float*)d_out;

  k_prep_all<<<13649, 256, 0, stream>>>((const unsigned char*)maskp, (const float4*)in_proj_w,
                                        out_proj_w, gate_w1, target, feats, support,
                                        ln_q_w, ln_q_b, ln_kv_w, ln_kv_b, out_proj_b,
                                        maskbf, (ushort4*)Wbf, Wobf, WoT, Wg1attn, Wg1ab,
                                        tgtfeats, qin, kvin, pbias);

  k_mm1<<<1024, 256, 0, stream>>>(qin, kvin, tgtfeats, Wg1attn, Wbf, Wg1ab, WoT,
                                  in_proj_b, gate_b1, qbuf, kvbuf, h1buf, Fbf);

  k_transpose_v<<<dim3(32, 16, 2), 256, 0, stream>>>(kvbuf, vtbuf);

  k_attn<<<1024, 256, 0, stream>>>(qbuf, kvbuf, vtbuf, maskbf, pot, plsum);
  k_combine_t<<<512, 256, 0, stream>>>(pot, plsum, ctx);

  k_mm2<<<512, 256, 0, stream>>>(ctx, Wobf, pbias, hc);

  k_gatefinal<<<2048, 256, 0, stream>>>(h1buf, hc, gate_w2, gate_b2, target,
                                        out_ln_w, out_ln_b, outp, outp + 2 * 1024 * 1024);
}